// Round 3
// baseline (698.092 us; speedup 1.0000x reference)
//
#include <hip/hip_runtime.h>

// FFT long conv: out[b,d,l] = (1/16384^2 forward-norm pair) * linear conv of x,f, masked.
// One workgroup per (b,d) channel; complex FFT 8192 in 64KB LDS.
//
// R4: 512-thread blocks to lift the VGPR cap (spill elimination, attempt 2).
//  * R2/R3 counters: WRITE >> FETCH phantom traffic (~1 GB write = ~512B/thread) with
//    VGPR_Count pinned at 64 despite launch_bounds(1024,4) AND amdgpu_waves_per_eu(4).
//    Diagnosis: scratch spills of the transient r[8] float2 around pass bodies; spill
//    writes evict dirty to HBM (counted in WRITE), fills hit L2 (FETCH small). Kernel is
//    BW-bound on its own spill traffic at ~3.9 TB/s.
//  * Fix: 1024 -> 512 threads/block (flat-workgroup-size 512 -> hard VGPR cap 256,
//    launch_bounds(512,4) targets 128 = 2x today's budget). Each thread now runs TWO
//    sequential radix-8 groups per pass: transient pressure unchanged, budget doubled.
//    2 blocks x 64KB LDS still co-resident -> same 16 waves/CU latency hiding.
//  * Reverted R3's nontemporal store (neutral-to-negative). Kept the x,f reload for the
//    odd spectrum (16 fewer persistent VGPRs; costs ~18us of L3-miss fetch, cheap vs spills).
//
// Structure (verified passing since R2, absmax 1.2e-4):
//  * radix-8-style merged passes: 13 radix-2 stages -> 4 LDS passes of 3 stages
//    (bits {12..10},{9..7},{6..4},{3..1}) + bit-0 stage via __shfl_xor (no LDS).
//  * one __sincosf per group per pass; LDS XOR swizzle i^(((i>>4)&7)<<1) hoisted via
//    known-zero-bit identities; pointwise iterates bit-reversed addresses (coalesced).
//
// positions arrives as int32 from the harness (int64 in the npz) - keep const int*.

#define N_FFT 8192
#define NT    512           // threads per block
#define NPT   16            // elements per thread
#define PI_F  3.14159265358979323846f
#define RS2   0.70710678118654752440f

__device__ __forceinline__ float2 cmul(float2 a, float2 b) {
    return make_float2(a.x * b.x - a.y * b.y, a.x * b.y + a.y * b.x);
}
__device__ __forceinline__ float2 cadd(float2 a, float2 b) { return make_float2(a.x + b.x, a.y + b.y); }
__device__ __forceinline__ float2 csub(float2 a, float2 b) { return make_float2(a.x - b.x, a.y - b.y); }
__device__ __forceinline__ float2 mneg_i(float2 a) { return make_float2(a.y, -a.x); }  // a * (-i)
__device__ __forceinline__ float2 mpos_i(float2 a) { return make_float2(-a.y, a.x); }  // a * (+i)

__device__ __forceinline__ int rev13(int v) { return (int)(__brev((unsigned)v) >> 19); }
// LDS bank swizzle: XOR bits 1..3 with bits 4..6 (float2 units). Bijective within [0,8192).
__device__ __forceinline__ int swz(int i) { return i ^ (((i >> 4) & 7) << 1); }

// Group ownership: group g (in [0,1024)) owns elements base + (k<<B), k=0..7, where
// base = (hi << (B+3)) | lo, lo = g & ((1<<B)-1), hi = g >> B.
// Swizzled-address identities (bits of k<<B never carry into the XOR field):
//   B>=7 : swz(base + (k<<B)) = swz(base) + (k<<B)
//   B==4 : swz(base + (k<<4)) = (base ^ (k<<1)) + (k<<4)
//   B==1 : swz(base + (k<<1)) = (base ^ mask) ^ (k<<1), mask = ((base>>4)&7)<<1
template <int B>
__device__ __forceinline__ int pass_base(int g) {
    const int lo   = g & ((1 << B) - 1);
    const int hi   = g >> B;
    const int base = (hi << (B + 3)) | lo;
    if constexpr (B == 4) return base;
    else                  return base ^ (((base >> 4) & 7) << 1);
}
template <int B>
__device__ __forceinline__ int pass_addr(int sb, int k) {
    if constexpr (B >= 7)      return sb + (k << B);
    else if constexpr (B == 4) return (sb ^ (k << 1)) + (k << 4);
    else                       return sb ^ (k << 1);
}

// ---- forward DIF merged group: stages B+2, B+1, B (descending).
//      LAST==true (B==1) appends stage 0 via shfl_xor (partner lane = lane^1). ----
template <int B, bool LAST>
__device__ __forceinline__ void fwd_group(float2* a, int g) {
    const int h  = 1 << B;
    const int lo = g & (h - 1);
    const int sb = pass_base<B>(g);
    float2 r[8];
#pragma unroll
    for (int k = 0; k < 8; ++k) r[k] = a[pass_addr<B>(sb, k)];

    float sn, cs;
    __sincosf(-PI_F * (float)lo / (float)(4 * h), &sn, &cs);
    const float2 T1  = make_float2(cs, sn);                    // e^{-i pi lo/(4h)}
    const float2 T2  = cmul(T1, T1);
    const float2 T4  = cmul(T2, T2);
    const float2 T1b = cmul(T1, make_float2(RS2, -RS2));       // T1 * e^{-i pi/4}

    // stage B+2: pairs (k,k+4), twiddle T1 * e^{-i pi k/4}
#pragma unroll
    for (int k = 0; k < 4; ++k) {
        float2 u = r[k], v = r[k + 4];
        r[k] = cadd(u, v);
        float2 d  = csub(u, v);
        float2 tw = (k == 0) ? T1 : (k == 1) ? T1b : (k == 2) ? mneg_i(T1) : mneg_i(T1b);
        r[k + 4] = cmul(d, tw);
    }
    // stage B+1: pairs (k,k+2), k in {0,1,4,5}, twiddle T2 * (k&1 ? -i : 1)
#pragma unroll
    for (int k0 = 0; k0 < 8; k0 += 4) {
#pragma unroll
        for (int kk = 0; kk < 2; ++kk) {
            const int k = k0 + kk;
            float2 u = r[k], v = r[k + 2];
            r[k] = cadd(u, v);
            r[k + 2] = cmul(csub(u, v), kk ? mneg_i(T2) : T2);
        }
    }
    // stage B: pairs (k,k+1), k even, twiddle T4
#pragma unroll
    for (int k = 0; k < 8; k += 2) {
        float2 u = r[k], v = r[k + 1];
        r[k] = cadd(u, v);
        r[k + 1] = cmul(csub(u, v), T4);
    }
    if (LAST) {  // stage 0 (half=1, twiddle 1): partner group g^1 -> lane^1, same k
        const float sgn = (g & 1) ? -1.0f : 1.0f;
#pragma unroll
        for (int k = 0; k < 8; ++k) {
            float ox = __shfl_xor(r[k].x, 1);
            float oy = __shfl_xor(r[k].y, 1);
            r[k].x = ox + sgn * r[k].x;
            r[k].y = oy + sgn * r[k].y;
        }
    }
#pragma unroll
    for (int k = 0; k < 8; ++k) a[pass_addr<B>(sb, k)] = r[k];
}

template <int B, bool LAST>
__device__ __forceinline__ void fwd_pass(float2* a, int t) {
    fwd_group<B, LAST>(a, t);
    fwd_group<B, LAST>(a, t + NT);
}

// ---- inverse DIT merged group: stages B, B+1, B+2 (ascending).
//      FIRST==true (B==1) prepends stage 0 via shfl_xor. STORE==false leaves result in r. ----
template <int B, bool FIRST, bool STORE>
__device__ __forceinline__ void inv_group(float2* a, int g, float2 r[8]) {
    const int h  = 1 << B;
    const int lo = g & (h - 1);
    const int sb = pass_base<B>(g);
#pragma unroll
    for (int k = 0; k < 8; ++k) r[k] = a[pass_addr<B>(sb, k)];

    if (FIRST) {
        const float sgn = (g & 1) ? -1.0f : 1.0f;
#pragma unroll
        for (int k = 0; k < 8; ++k) {
            float ox = __shfl_xor(r[k].x, 1);
            float oy = __shfl_xor(r[k].y, 1);
            r[k].x = ox + sgn * r[k].x;
            r[k].y = oy + sgn * r[k].y;
        }
    }
    float sn, cs;
    __sincosf(PI_F * (float)lo / (float)(4 * h), &sn, &cs);
    const float2 U1  = make_float2(cs, sn);                    // e^{+i pi lo/(4h)}
    const float2 U2  = cmul(U1, U1);
    const float2 U4  = cmul(U2, U2);
    const float2 U1b = cmul(U1, make_float2(RS2, RS2));        // U1 * e^{+i pi/4}

    // stage B: pairs (k,k+1), k even, v twiddled by U4
#pragma unroll
    for (int k = 0; k < 8; k += 2) {
        float2 u = r[k];
        float2 v = cmul(r[k + 1], U4);
        r[k] = cadd(u, v);
        r[k + 1] = csub(u, v);
    }
    // stage B+1: pairs (k,k+2), k in {0,1,4,5}, twiddle U2 * (k&1 ? +i : 1)
#pragma unroll
    for (int k0 = 0; k0 < 8; k0 += 4) {
#pragma unroll
        for (int kk = 0; kk < 2; ++kk) {
            const int k = k0 + kk;
            float2 u = r[k];
            float2 v = cmul(r[k + 2], kk ? mpos_i(U2) : U2);
            r[k] = cadd(u, v);
            r[k + 2] = csub(u, v);
        }
    }
    // stage B+2: pairs (k,k+4), twiddle U1 * e^{+i pi k/4}
#pragma unroll
    for (int k = 0; k < 4; ++k) {
        float2 tw = (k == 0) ? U1 : (k == 1) ? U1b : (k == 2) ? mpos_i(U1) : mpos_i(U1b);
        float2 u = r[k];
        float2 v = cmul(r[k + 4], tw);
        r[k] = cadd(u, v);
        r[k + 4] = csub(u, v);
    }
    if (STORE) {
#pragma unroll
        for (int k = 0; k < 8; ++k) a[pass_addr<B>(sb, k)] = r[k];
    }
}

template <int B, bool FIRST>
__device__ __forceinline__ void inv_pass(float2* a, int t) {
    float2 r[8];
    inv_group<B, FIRST, true>(a, t, r);
    inv_group<B, FIRST, true>(a, t + NT, r);
}

// Z1 = W_k, Z2 = W_{N-k} of combined x+i*f spectrum -> Yhat_k = Xhat_k*Fhat_k*scale.
__device__ __forceinline__ float2 pw(float2 z1, float2 z2, float scale) {
    float2 X = make_float2(0.5f * (z1.x + z2.x), 0.5f * (z1.y - z2.y));
    float2 D = make_float2(z1.x - z2.x, z1.y + z2.y);
    float2 F = make_float2(0.5f * D.y, -0.5f * D.x);
    float2 Y = cmul(X, F);
    return make_float2(Y.x * scale, Y.y * scale);
}

__global__ void __launch_bounds__(NT, 4)
fftconv_kernel(const float* __restrict__ x, const float* __restrict__ f,
               const int* __restrict__ pos, float* __restrict__ out) {
    __shared__ float2 a[N_FFT];                 // 64 KiB
    const int t  = threadIdx.x;
    const int c  = blockIdx.x;                  // channel b*256 + d
    const int bb = c >> 8;
    const size_t gbase = (size_t)c * N_FFT;
    const int* pbase = pos + (size_t)bb * N_FFT;

    const float scale = 1.0f / (16384.0f * 16384.0f);  // two forward-norm 1/n factors

    // swz(q*512 + t) = swz(t) + q*512  (bits 4..6 come from t; q*512 is bits >= 9)
    const int st = swz(t);

    float  yr[NPT];  // stashed Re(ye), element m = (i*512+t) + k*1024 at yr[i*8+k]
    float2 r[8];

    // cos/sin(pi*q/16) for the odd-spectrum modulation (m = q*512 + t)
    const float C16[16] = { 1.0f, 0.98078528f, 0.92387953f, 0.83146961f,
                            0.70710678f, 0.55557023f, 0.38268343f, 0.19509032f,
                            0.0f, -0.19509032f, -0.38268343f, -0.55557023f,
                           -0.70710678f, -0.83146961f, -0.92387953f, -0.98078528f };
    const float S16[16] = { 0.0f, 0.19509032f, 0.38268343f, 0.55557023f,
                            0.70710678f, 0.83146961f, 0.92387953f, 0.98078528f,
                            1.0f, 0.98078528f, 0.92387953f, 0.83146961f,
                            0.70710678f, 0.55557023f, 0.38268343f, 0.19509032f };
    // cos/sin(pi*k/8) for the final combine (m = g + k*1024)
    const float C8[8] = {1.0f, 0.92387953f, 0.70710678f, 0.38268343f,
                         0.0f, -0.38268343f, -0.70710678f, -0.92387953f};
    const float S8[8] = {0.0f, 0.38268343f, 0.70710678f, 0.92387953f,
                         1.0f, 0.92387953f, 0.70710678f, 0.38268343f};

    // ---- load x,f; pack w = x + i f (natural order) ----
#pragma unroll
    for (int q = 0; q < NPT; ++q) {
        const int m = q * NT + t;
        a[st + q * NT] = make_float2(x[gbase + m], f[gbase + m]);
    }
    __syncthreads();

    // ---- even spectrum: FFT_8192(w), bit-reversed order ----
    fwd_pass<10, false>(a, t); __syncthreads();
    fwd_pass<7,  false>(a, t); __syncthreads();
    fwd_pass<4,  false>(a, t); __syncthreads();
    fwd_pass<1,  true >(a, t); __syncthreads();

    // ---- even pointwise, iterated by bit-reversed address p1 = 2e (<=> j < 4096) ----
#pragma unroll
    for (int q = 0; q < 8; ++q) {
        const int e  = q * NT + t;
        const int p1 = 2 * e;
        if (e == 0) {  // j=4096 self-pair lives at odd address 1 (never enumerated below)
            float2 z = a[swz(1)];
            a[swz(1)] = pw(z, z, scale);
        }
        const int j  = rev13(p1);                          // j in [0,4095]
        const int p2 = rev13((N_FFT - j) & (N_FFT - 1));   // partner addr (odd); j=0 -> p2=p1=0
        float2 z1 = a[swz(p1)];
        float2 z2 = a[swz(p2)];
        float2 Y  = pw(z1, z2, scale);
        a[swz(p1)] = Y;
        a[swz(p2)] = make_float2(Y.x, -Y.y);
    }
    __syncthreads();

    // ---- ye = IDFT(Yhat_even); keep Re in registers (no LDS writeback on last pass) ----
    inv_pass<1, true >(a, t); __syncthreads();
    inv_pass<4, false>(a, t); __syncthreads();
    inv_pass<7, false>(a, t); __syncthreads();
#pragma unroll
    for (int i = 0; i < 2; ++i) {
        inv_group<10, false, false>(a, i * NT + t, r);
#pragma unroll
        for (int k = 0; k < 8; ++k) yr[i * 8 + k] = r[k].x;   // element m = (i*512+t) + k*1024
    }
    __syncthreads();  // all reads of a[] done before odd modulate overwrites

    // ---- odd spectrum input: w * e^{-i pi m / 8192}, m = q*512 + t ----
    // w re-loaded from global (this block read the same 64KB above) instead of a register
    // stash: -32 persistent VGPRs at NPT=16, the reload is mostly L2/L3 traffic.
    {
        float sn, cs;
        __sincosf(-PI_F * (float)t / 8192.0f, &sn, &cs);
        const float2 Bt = make_float2(cs, sn);
#pragma unroll
        for (int q = 0; q < NPT; ++q) {
            const int m = q * NT + t;
            const float2 wq = make_float2(x[gbase + m], f[gbase + m]);
            const float2 tw = cmul(Bt, make_float2(C16[q], -S16[q]));  // e^{-i pi (t + 512q)/8192}
            a[st + q * NT] = cmul(wq, tw);
        }
    }
    __syncthreads();

    fwd_pass<10, false>(a, t); __syncthreads();
    fwd_pass<7,  false>(a, t); __syncthreads();
    fwd_pass<4,  false>(a, t); __syncthreads();
    fwd_pass<1,  true >(a, t); __syncthreads();

    // ---- odd pointwise: partner of addr p1 is 8191 - p1 (rev13 of complement) ----
#pragma unroll
    for (int q = 0; q < 8; ++q) {
        const int e  = q * NT + t;
        const int p1 = 2 * e;
        const int p2 = N_FFT - 1 - p1;
        float2 z1 = a[swz(p1)];
        float2 z2 = a[swz(p2)];
        float2 Y  = pw(z1, z2, scale);
        a[swz(p1)] = Y;
        a[swz(p2)] = make_float2(Y.x, -Y.y);
    }
    __syncthreads();

    // ---- yo = IDFT(Yhat_odd) ----
    inv_pass<1, true >(a, t); __syncthreads();
    inv_pass<4, false>(a, t); __syncthreads();
    inv_pass<7, false>(a, t); __syncthreads();

    // ---- final pass per group + combine y_m = Re(ye) + Re(e^{+i pi m/8192} * yo) ----
#pragma unroll
    for (int i = 0; i < 2; ++i) {
        const int g = i * NT + t;
        inv_group<10, false, false>(a, g, r);
        float sn, cs;
        __sincosf(PI_F * (float)g / 8192.0f, &sn, &cs);
        const float2 Bt = make_float2(cs, sn);
#pragma unroll
        for (int k = 0; k < 8; ++k) {
            const int m = k * 1024 + g;
            const float2 tw = cmul(Bt, make_float2(C8[k], S8[k]));   // e^{+i pi m/8192}
            const float val = yr[i * 8 + k] + tw.x * r[k].x - tw.y * r[k].y;
            const float msk = (pbase[m] != -1) ? 1.0f : 0.0f;
            out[gbase + m] = val * msk;
        }
    }
}

extern "C" void kernel_launch(void* const* d_in, const int* in_sizes, int n_in,
                              void* d_out, int out_size, void* d_ws, size_t ws_size,
                              hipStream_t stream) {
    const float* x   = (const float*)d_in[0];
    const float* f   = (const float*)d_in[1];
    const int*   pos = (const int*)d_in[2];
    float*       out = (float*)d_out;
    (void)in_sizes; (void)n_in; (void)out_size; (void)d_ws; (void)ws_size;

    // B*D = 8*256 = 2048 channels, one block each
    fftconv_kernel<<<2048, NT, 0, stream>>>(x, f, pos, out);
}

// Round 4
// 327.742 us; speedup vs baseline: 2.1300x; 2.1300x over previous
//
#include <hip/hip_runtime.h>

// FFT long conv: out[b,d,l] = (1/16384^2 forward-norm pair) * linear conv of x,f, masked.
// One workgroup per (b,d) channel; complex FFT 8192 in 64KB LDS.
//
// R5: split even/odd pipelines into TWO kernels to eliminate all cross-phase register
// state (spill elimination, attempt 3 -- this one removes the possibility structurally).
//  * Evidence: WRITE_SIZE ~1.1-1.2 GB (vs 64 MB output) across R2/R3/R4, immune to
//    launch_bounds/waves_per_eu/block-shape changes; VGPR_Count pinned at 64; occupancy
//    pinned at ~1 block/CU. Hypothesis: per-thread scratch for state that persists
//    across the ~19 barrier segments (w[]/yr[] stashes), whose writebacks evict to HBM
//    and whose backing store caps resident waves.
//  * Fix: kernel1 computes ye (even half-spectrum pipeline) and stores it to out;
//    kernel2 computes yo (odd pipeline), reads out, combines, masks, stores final.
//    Neither kernel keeps ANY register state across barrier segments: transient r[8]
//    + twiddles (~40 VGPRs) only. Zero scratch possible. Costs one extra 64MB read of
//    out + a 128MB re-read of x,f (L3-resident), saves ~1GB phantom traffic if theory
//    holds, and should unlock 2 blocks/CU (barrier stalls of one block hide under the
//    other).
//  * Reverted R4's 512-thread shape (regressed): back to 1024 threads, NPT=8, the
//    best-measured configuration (R2 dispatches 435us).
//
// Structure per FFT (verified passing since R2, absmax 1.2e-4):
//  * radix-8-style merged passes: 13 radix-2 stages -> 4 LDS passes of 3 stages
//    (bits {12..10},{9..7},{6..4},{3..1}) + bit-0 stage via __shfl_xor (no LDS).
//  * one __sincosf per pass; LDS XOR swizzle i^(((i>>4)&7)<<1) hoisted via known-zero-
//    bit identities; pointwise iterates bit-reversed addresses (coalesced hermitian
//    pairing).
//
// positions arrives as int32 from the harness (int64 in the npz) - keep const int*.

#define N_FFT 8192
#define NT    1024          // threads per block
#define NPT   8             // elements per thread
#define PI_F  3.14159265358979323846f
#define RS2   0.70710678118654752440f

__device__ __forceinline__ float2 cmul(float2 a, float2 b) {
    return make_float2(a.x * b.x - a.y * b.y, a.x * b.y + a.y * b.x);
}
__device__ __forceinline__ float2 cadd(float2 a, float2 b) { return make_float2(a.x + b.x, a.y + b.y); }
__device__ __forceinline__ float2 csub(float2 a, float2 b) { return make_float2(a.x - b.x, a.y - b.y); }
__device__ __forceinline__ float2 mneg_i(float2 a) { return make_float2(a.y, -a.x); }  // a * (-i)
__device__ __forceinline__ float2 mpos_i(float2 a) { return make_float2(-a.y, a.x); }  // a * (+i)

__device__ __forceinline__ int rev13(int v) { return (int)(__brev((unsigned)v) >> 19); }
// LDS bank swizzle: XOR bits 1..3 with bits 4..6 (float2 units). Bijective within [0,8192).
__device__ __forceinline__ int swz(int i) { return i ^ (((i >> 4) & 7) << 1); }

// Pass ownership: thread t owns elements base + (k<<B), k=0..7, where
// base = (hi << (B+3)) | lo, lo = t & ((1<<B)-1), hi = t >> B.
// Swizzled-address identities (bits of k<<B never carry into the XOR field):
//   B>=7 : swz(base + (k<<B)) = swz(base) + (k<<B)
//   B==4 : swz(base + (k<<4)) = (base ^ (k<<1)) + (k<<4)
//   B==1 : swz(base + (k<<1)) = (base ^ mask) ^ (k<<1), mask = ((base>>4)&7)<<1
template <int B>
__device__ __forceinline__ int pass_base(int t) {
    const int lo   = t & ((1 << B) - 1);
    const int hi   = t >> B;
    const int base = (hi << (B + 3)) | lo;
    if constexpr (B == 4) return base;
    else                  return base ^ (((base >> 4) & 7) << 1);
}
template <int B>
__device__ __forceinline__ int pass_addr(int sb, int k) {
    if constexpr (B >= 7)      return sb + (k << B);
    else if constexpr (B == 4) return (sb ^ (k << 1)) + (k << 4);
    else                       return sb ^ (k << 1);
}

// ---- forward DIF merged pass: stages B+2, B+1, B (descending).
//      LAST==true (B==1) appends stage 0 via shfl_xor (partner lane = lane^1). ----
template <int B, bool LAST>
__device__ __forceinline__ void fwd_pass(float2* a, int t) {
    const int h  = 1 << B;
    const int lo = t & (h - 1);
    const int sb = pass_base<B>(t);
    float2 r[8];
#pragma unroll
    for (int k = 0; k < 8; ++k) r[k] = a[pass_addr<B>(sb, k)];

    float sn, cs;
    __sincosf(-PI_F * (float)lo / (float)(4 * h), &sn, &cs);
    const float2 T1  = make_float2(cs, sn);                    // e^{-i pi lo/(4h)}
    const float2 T2  = cmul(T1, T1);
    const float2 T4  = cmul(T2, T2);
    const float2 T1b = cmul(T1, make_float2(RS2, -RS2));       // T1 * e^{-i pi/4}

    // stage B+2: pairs (k,k+4), twiddle T1 * e^{-i pi k/4}
#pragma unroll
    for (int k = 0; k < 4; ++k) {
        float2 u = r[k], v = r[k + 4];
        r[k] = cadd(u, v);
        float2 d  = csub(u, v);
        float2 tw = (k == 0) ? T1 : (k == 1) ? T1b : (k == 2) ? mneg_i(T1) : mneg_i(T1b);
        r[k + 4] = cmul(d, tw);
    }
    // stage B+1: pairs (k,k+2), k in {0,1,4,5}, twiddle T2 * (k&1 ? -i : 1)
#pragma unroll
    for (int k0 = 0; k0 < 8; k0 += 4) {
#pragma unroll
        for (int kk = 0; kk < 2; ++kk) {
            const int k = k0 + kk;
            float2 u = r[k], v = r[k + 2];
            r[k] = cadd(u, v);
            r[k + 2] = cmul(csub(u, v), kk ? mneg_i(T2) : T2);
        }
    }
    // stage B: pairs (k,k+1), k even, twiddle T4
#pragma unroll
    for (int k = 0; k < 8; k += 2) {
        float2 u = r[k], v = r[k + 1];
        r[k] = cadd(u, v);
        r[k + 1] = cmul(csub(u, v), T4);
    }
    if (LAST) {  // stage 0 (half=1, twiddle 1): partner is lane t^1, same k
        const float sgn = (t & 1) ? -1.0f : 1.0f;
#pragma unroll
        for (int k = 0; k < 8; ++k) {
            float ox = __shfl_xor(r[k].x, 1);
            float oy = __shfl_xor(r[k].y, 1);
            r[k].x = ox + sgn * r[k].x;
            r[k].y = oy + sgn * r[k].y;
        }
    }
#pragma unroll
    for (int k = 0; k < 8; ++k) a[pass_addr<B>(sb, k)] = r[k];
}

// ---- inverse DIT merged pass: stages B, B+1, B+2 (ascending).
//      FIRST==true (B==1) prepends stage 0 via shfl_xor. STORE==false leaves result in r. ----
template <int B, bool FIRST, bool STORE>
__device__ __forceinline__ void inv_pass(float2* a, int t, float2 r[8]) {
    const int h  = 1 << B;
    const int lo = t & (h - 1);
    const int sb = pass_base<B>(t);
#pragma unroll
    for (int k = 0; k < 8; ++k) r[k] = a[pass_addr<B>(sb, k)];

    if (FIRST) {
        const float sgn = (t & 1) ? -1.0f : 1.0f;
#pragma unroll
        for (int k = 0; k < 8; ++k) {
            float ox = __shfl_xor(r[k].x, 1);
            float oy = __shfl_xor(r[k].y, 1);
            r[k].x = ox + sgn * r[k].x;
            r[k].y = oy + sgn * r[k].y;
        }
    }
    float sn, cs;
    __sincosf(PI_F * (float)lo / (float)(4 * h), &sn, &cs);
    const float2 U1  = make_float2(cs, sn);                    // e^{+i pi lo/(4h)}
    const float2 U2  = cmul(U1, U1);
    const float2 U4  = cmul(U2, U2);
    const float2 U1b = cmul(U1, make_float2(RS2, RS2));        // U1 * e^{+i pi/4}

    // stage B: pairs (k,k+1), k even, v twiddled by U4
#pragma unroll
    for (int k = 0; k < 8; k += 2) {
        float2 u = r[k];
        float2 v = cmul(r[k + 1], U4);
        r[k] = cadd(u, v);
        r[k + 1] = csub(u, v);
    }
    // stage B+1: pairs (k,k+2), k in {0,1,4,5}, twiddle U2 * (k&1 ? +i : 1)
#pragma unroll
    for (int k0 = 0; k0 < 8; k0 += 4) {
#pragma unroll
        for (int kk = 0; kk < 2; ++kk) {
            const int k = k0 + kk;
            float2 u = r[k];
            float2 v = cmul(r[k + 2], kk ? mpos_i(U2) : U2);
            r[k] = cadd(u, v);
            r[k + 2] = csub(u, v);
        }
    }
    // stage B+2: pairs (k,k+4), twiddle U1 * e^{+i pi k/4}
#pragma unroll
    for (int k = 0; k < 4; ++k) {
        float2 tw = (k == 0) ? U1 : (k == 1) ? U1b : (k == 2) ? mpos_i(U1) : mpos_i(U1b);
        float2 u = r[k];
        float2 v = cmul(r[k + 4], tw);
        r[k] = cadd(u, v);
        r[k + 4] = csub(u, v);
    }
    if (STORE) {
#pragma unroll
        for (int k = 0; k < 8; ++k) a[pass_addr<B>(sb, k)] = r[k];
    }
}

// Z1 = W_k, Z2 = W_{N-k} of combined x+i*f spectrum -> Yhat_k = Xhat_k*Fhat_k*scale.
__device__ __forceinline__ float2 pw(float2 z1, float2 z2, float scale) {
    float2 X = make_float2(0.5f * (z1.x + z2.x), 0.5f * (z1.y - z2.y));
    float2 D = make_float2(z1.x - z2.x, z1.y + z2.y);
    float2 F = make_float2(0.5f * D.y, -0.5f * D.x);
    float2 Y = cmul(X, F);
    return make_float2(Y.x * scale, Y.y * scale);
}

// ============================ kernel 1: even pipeline ============================
// ye = IDFT_8192( pointwise_even( FFT_8192(x + i f) ) ); store Re(ye) to out (unmasked).
__global__ void __launch_bounds__(NT)
fftconv_even(const float* __restrict__ x, const float* __restrict__ f,
             float* __restrict__ out) {
    __shared__ float2 a[N_FFT];                 // 64 KiB
    const int t = threadIdx.x;
    const size_t gbase = (size_t)blockIdx.x * N_FFT;
    const float scale = 1.0f / (16384.0f * 16384.0f);  // two forward-norm 1/n factors
    const int st = swz(t);
    float2 r[8];

    // ---- load x,f; pack w = x + i f (natural order) ----
#pragma unroll
    for (int q = 0; q < NPT; ++q) {
        const int m = q * NT + t;
        a[st + q * NT] = make_float2(x[gbase + m], f[gbase + m]);
    }
    __syncthreads();

    // ---- even spectrum: FFT_8192(w), bit-reversed order ----
    fwd_pass<10, false>(a, t); __syncthreads();
    fwd_pass<7,  false>(a, t); __syncthreads();
    fwd_pass<4,  false>(a, t); __syncthreads();
    fwd_pass<1,  true >(a, t); __syncthreads();

    // ---- even pointwise, iterated by bit-reversed address p1 = 2e (<=> j < 4096) ----
#pragma unroll
    for (int q = 0; q < 4; ++q) {
        const int e  = q * NT + t;
        const int p1 = 2 * e;
        if (e == 0) {  // j=4096 self-pair lives at odd address 1 (never enumerated below)
            float2 z = a[swz(1)];
            a[swz(1)] = pw(z, z, scale);
        }
        const int j  = rev13(p1);                          // j in [0,4095]
        const int p2 = rev13((N_FFT - j) & (N_FFT - 1));   // partner addr (odd); j=0 -> p2=p1=0
        float2 z1 = a[swz(p1)];
        float2 z2 = a[swz(p2)];
        float2 Y  = pw(z1, z2, scale);
        a[swz(p1)] = Y;
        a[swz(p2)] = make_float2(Y.x, -Y.y);
    }
    __syncthreads();

    // ---- ye = IDFT(Yhat_even); last pass keeps result in registers ----
    inv_pass<1,  true,  true >(a, t, r); __syncthreads();
    inv_pass<4,  false, true >(a, t, r); __syncthreads();
    inv_pass<7,  false, true >(a, t, r); __syncthreads();
    inv_pass<10, false, false>(a, t, r);

    // r[k] holds element m = k*1024 + t; store Re(ye) as the partial result.
#pragma unroll
    for (int k = 0; k < 8; ++k) {
        out[gbase + (size_t)(k * NT + t)] = r[k].x;
    }
}

// ============================ kernel 2: odd pipeline + combine ============================
// yo = IDFT_8192( pointwise_odd( FFT_8192((x + i f) * e^{-i pi m/8192}) ) );
// out = (out + Re(e^{+i pi m/8192} * yo)) * mask.
__global__ void __launch_bounds__(NT)
fftconv_odd(const float* __restrict__ x, const float* __restrict__ f,
            const int* __restrict__ pos, float* __restrict__ out) {
    __shared__ float2 a[N_FFT];                 // 64 KiB
    const int t = threadIdx.x;
    const int c = blockIdx.x;                   // channel b*256 + d
    const int bb = c >> 8;
    const size_t gbase = (size_t)c * N_FFT;
    const int* pbase = pos + (size_t)bb * N_FFT;
    const float scale = 1.0f / (16384.0f * 16384.0f);
    const int st = swz(t);
    float2 r[8];

    // cos/sin(pi*k/8) for modulate (m = q*1024 + t) and combine (m = k*1024 + t)
    const float C8[8] = {1.0f, 0.92387953f, 0.70710678f, 0.38268343f,
                         0.0f, -0.38268343f, -0.70710678f, -0.92387953f};
    const float S8[8] = {0.0f, 0.38268343f, 0.70710678f, 0.92387953f,
                         1.0f, 0.92387953f, 0.70710678f, 0.38268343f};

    // ---- load x,f; modulate w * e^{-i pi m / 8192} on the fly ----
    {
        float sn, cs;
        __sincosf(-PI_F * (float)t / 8192.0f, &sn, &cs);
        const float2 Bt = make_float2(cs, sn);
#pragma unroll
        for (int q = 0; q < NPT; ++q) {
            const int m = q * NT + t;
            const float2 wq = make_float2(x[gbase + m], f[gbase + m]);
            const float2 tw = cmul(Bt, make_float2(C8[q], -S8[q]));  // e^{-i pi (t+1024q)/8192}
            a[st + q * NT] = cmul(wq, tw);
        }
    }
    __syncthreads();

    // ---- odd spectrum: FFT_8192, bit-reversed order ----
    fwd_pass<10, false>(a, t); __syncthreads();
    fwd_pass<7,  false>(a, t); __syncthreads();
    fwd_pass<4,  false>(a, t); __syncthreads();
    fwd_pass<1,  true >(a, t); __syncthreads();

    // ---- odd pointwise: partner of addr p1 is 8191 - p1 (rev13 of complement) ----
#pragma unroll
    for (int q = 0; q < 4; ++q) {
        const int e  = q * NT + t;
        const int p1 = 2 * e;
        const int p2 = N_FFT - 1 - p1;
        float2 z1 = a[swz(p1)];
        float2 z2 = a[swz(p2)];
        float2 Y  = pw(z1, z2, scale);
        a[swz(p1)] = Y;
        a[swz(p2)] = make_float2(Y.x, -Y.y);
    }
    __syncthreads();

    // ---- yo = IDFT(Yhat_odd); last pass keeps result in registers ----
    inv_pass<1,  true,  true >(a, t, r); __syncthreads();
    inv_pass<4,  false, true >(a, t, r); __syncthreads();
    inv_pass<7,  false, true >(a, t, r); __syncthreads();
    inv_pass<10, false, false>(a, t, r);

    // ---- combine: y_m = ye_m + Re(e^{+i pi m/8192} * yo_m), mask, store ----
    {
        float sn, cs;
        __sincosf(PI_F * (float)t / 8192.0f, &sn, &cs);
        const float2 Bt = make_float2(cs, sn);
#pragma unroll
        for (int k = 0; k < 8; ++k) {
            const int m = k * NT + t;
            const float2 tw = cmul(Bt, make_float2(C8[k], S8[k]));   // e^{+i pi m/8192}
            const float ye = out[gbase + m];
            const float val = ye + tw.x * r[k].x - tw.y * r[k].y;
            const float msk = (pbase[m] != -1) ? 1.0f : 0.0f;
            out[gbase + m] = val * msk;
        }
    }
}

extern "C" void kernel_launch(void* const* d_in, const int* in_sizes, int n_in,
                              void* d_out, int out_size, void* d_ws, size_t ws_size,
                              hipStream_t stream) {
    const float* x   = (const float*)d_in[0];
    const float* f   = (const float*)d_in[1];
    const int*   pos = (const int*)d_in[2];
    float*       out = (float*)d_out;
    (void)in_sizes; (void)n_in; (void)out_size; (void)d_ws; (void)ws_size;

    // B*D = 8*256 = 2048 channels, one block each, two pipeline kernels
    fftconv_even<<<2048, NT, 0, stream>>>(x, f, out);
    fftconv_odd <<<2048, NT, 0, stream>>>(x, f, pos, out);
}

// Round 5
// 272.568 us; speedup vs baseline: 2.5612x; 1.2024x over previous
//
#include <hip/hip_runtime.h>

// FFT long conv: out[b,d,l] = (1/16384^2 forward-norm pair) * linear conv of x,f, masked.
// One workgroup per (b,d) channel.
//
// R6: fused 3-FFT algorithm (was 4 FFTs across 2 kernels).
//  * R5 post-mortem: spill theory CONFIRMED (WRITE 1.18GB -> 64MB exactly, VGPR 40,
//    dur 594->327us). Rule: no register state may cross a barrier segment (small Gv[]
//    in the pack step is the one deliberate 24-VGPR exception, well under the 64 cap).
//  * New: inverse side packed as a single complex IFFT (standard irfft packing):
//      Ghat_k = (P_k + conj(Q_k)) + i e^{i pi k/8192} (P_k - conj(Q_k)),  Q_k = Yprod_{8192-k}
//      c = IDFT_8192(Ghat)  ->  c_j = y_{2j} + i y_{2j+1}   (verified on analytic spectra)
//    so 2 fwd + 1 inv = 3 FFTs (-25% FFT work), no ye HBM round-trip, no combine pass.
//  * Fused single kernel, 128KB LDS (A=We, B=Wo). Occupancy was already ~1 block/CU at
//    64KB (measured 42-45%), so doubling LDS costs nothing. A/B forward passes share
//    barriers: 10 barriers total vs 18.
//  * Pack thread->cluster map j=(q<<10)|((t&7)<<7)|(t>>3) puts lane-varying t-bits into
//    rev13(j)'s bank bits: ~8-way instead of 32-way LDS conflicts on the scattered reads.
//  * Output stored as coalesced float2 (y_{2j},y_{2j+1}); mask read as int2.
//
// positions arrives as int32 from the harness (int64 in the npz) - keep const int*.

#define N_FFT 8192
#define NT    1024          // threads per block
#define NPT   8             // elements per thread
#define PI_F  3.14159265358979323846f
#define RS2   0.70710678118654752440f

__device__ __forceinline__ float2 cmul(float2 a, float2 b) {
    return make_float2(a.x * b.x - a.y * b.y, a.x * b.y + a.y * b.x);
}
__device__ __forceinline__ float2 cadd(float2 a, float2 b) { return make_float2(a.x + b.x, a.y + b.y); }
__device__ __forceinline__ float2 csub(float2 a, float2 b) { return make_float2(a.x - b.x, a.y - b.y); }
__device__ __forceinline__ float2 mneg_i(float2 a) { return make_float2(a.y, -a.x); }  // a * (-i)
__device__ __forceinline__ float2 mpos_i(float2 a) { return make_float2(-a.y, a.x); }  // a * (+i)

__device__ __forceinline__ int rev13(int v) { return (int)(__brev((unsigned)v) >> 19); }
// LDS bank swizzle: XOR bits 1..3 with bits 4..6 (float2 units). Bijective within [0,8192).
__device__ __forceinline__ int swz(int i) { return i ^ (((i >> 4) & 7) << 1); }

// Pass ownership: thread t owns elements base + (k<<B), k=0..7, where
// base = (hi << (B+3)) | lo, lo = t & ((1<<B)-1), hi = t >> B.
// Swizzled-address identities (bits of k<<B never carry into the XOR field):
//   B>=7 : swz(base + (k<<B)) = swz(base) + (k<<B)
//   B==4 : swz(base + (k<<4)) = (base ^ (k<<1)) + (k<<4)
//   B==1 : swz(base + (k<<1)) = (base ^ mask) ^ (k<<1), mask = ((base>>4)&7)<<1
template <int B>
__device__ __forceinline__ int pass_base(int t) {
    const int lo   = t & ((1 << B) - 1);
    const int hi   = t >> B;
    const int base = (hi << (B + 3)) | lo;
    if constexpr (B == 4) return base;
    else                  return base ^ (((base >> 4) & 7) << 1);
}
template <int B>
__device__ __forceinline__ int pass_addr(int sb, int k) {
    if constexpr (B >= 7)      return sb + (k << B);
    else if constexpr (B == 4) return (sb ^ (k << 1)) + (k << 4);
    else                       return sb ^ (k << 1);
}

// ---- forward DIF merged pass: stages B+2, B+1, B (descending).
//      LAST==true (B==1) appends stage 0 via shfl_xor (partner lane = lane^1). ----
template <int B, bool LAST>
__device__ __forceinline__ void fwd_pass(float2* a, int t) {
    const int h  = 1 << B;
    const int lo = t & (h - 1);
    const int sb = pass_base<B>(t);
    float2 r[8];
#pragma unroll
    for (int k = 0; k < 8; ++k) r[k] = a[pass_addr<B>(sb, k)];

    float sn, cs;
    __sincosf(-PI_F * (float)lo / (float)(4 * h), &sn, &cs);
    const float2 T1  = make_float2(cs, sn);                    // e^{-i pi lo/(4h)}
    const float2 T2  = cmul(T1, T1);
    const float2 T4  = cmul(T2, T2);
    const float2 T1b = cmul(T1, make_float2(RS2, -RS2));       // T1 * e^{-i pi/4}

    // stage B+2: pairs (k,k+4), twiddle T1 * e^{-i pi k/4}
#pragma unroll
    for (int k = 0; k < 4; ++k) {
        float2 u = r[k], v = r[k + 4];
        r[k] = cadd(u, v);
        float2 d  = csub(u, v);
        float2 tw = (k == 0) ? T1 : (k == 1) ? T1b : (k == 2) ? mneg_i(T1) : mneg_i(T1b);
        r[k + 4] = cmul(d, tw);
    }
    // stage B+1: pairs (k,k+2), k in {0,1,4,5}, twiddle T2 * (k&1 ? -i : 1)
#pragma unroll
    for (int k0 = 0; k0 < 8; k0 += 4) {
#pragma unroll
        for (int kk = 0; kk < 2; ++kk) {
            const int k = k0 + kk;
            float2 u = r[k], v = r[k + 2];
            r[k] = cadd(u, v);
            r[k + 2] = cmul(csub(u, v), kk ? mneg_i(T2) : T2);
        }
    }
    // stage B: pairs (k,k+1), k even, twiddle T4
#pragma unroll
    for (int k = 0; k < 8; k += 2) {
        float2 u = r[k], v = r[k + 1];
        r[k] = cadd(u, v);
        r[k + 1] = cmul(csub(u, v), T4);
    }
    if (LAST) {  // stage 0 (half=1, twiddle 1): partner is lane t^1, same k
        const float sgn = (t & 1) ? -1.0f : 1.0f;
#pragma unroll
        for (int k = 0; k < 8; ++k) {
            float ox = __shfl_xor(r[k].x, 1);
            float oy = __shfl_xor(r[k].y, 1);
            r[k].x = ox + sgn * r[k].x;
            r[k].y = oy + sgn * r[k].y;
        }
    }
#pragma unroll
    for (int k = 0; k < 8; ++k) a[pass_addr<B>(sb, k)] = r[k];
}

// ---- inverse DIT merged pass: stages B, B+1, B+2 (ascending).
//      FIRST==true (B==1) prepends stage 0 via shfl_xor. STORE==false leaves result in r. ----
template <int B, bool FIRST, bool STORE>
__device__ __forceinline__ void inv_pass(float2* a, int t, float2 r[8]) {
    const int h  = 1 << B;
    const int lo = t & (h - 1);
    const int sb = pass_base<B>(t);
#pragma unroll
    for (int k = 0; k < 8; ++k) r[k] = a[pass_addr<B>(sb, k)];

    if (FIRST) {
        const float sgn = (t & 1) ? -1.0f : 1.0f;
#pragma unroll
        for (int k = 0; k < 8; ++k) {
            float ox = __shfl_xor(r[k].x, 1);
            float oy = __shfl_xor(r[k].y, 1);
            r[k].x = ox + sgn * r[k].x;
            r[k].y = oy + sgn * r[k].y;
        }
    }
    float sn, cs;
    __sincosf(PI_F * (float)lo / (float)(4 * h), &sn, &cs);
    const float2 U1  = make_float2(cs, sn);                    // e^{+i pi lo/(4h)}
    const float2 U2  = cmul(U1, U1);
    const float2 U4  = cmul(U2, U2);
    const float2 U1b = cmul(U1, make_float2(RS2, RS2));        // U1 * e^{+i pi/4}

    // stage B: pairs (k,k+1), k even, v twiddled by U4
#pragma unroll
    for (int k = 0; k < 8; k += 2) {
        float2 u = r[k];
        float2 v = cmul(r[k + 1], U4);
        r[k] = cadd(u, v);
        r[k + 1] = csub(u, v);
    }
    // stage B+1: pairs (k,k+2), k in {0,1,4,5}, twiddle U2 * (k&1 ? +i : 1)
#pragma unroll
    for (int k0 = 0; k0 < 8; k0 += 4) {
#pragma unroll
        for (int kk = 0; kk < 2; ++kk) {
            const int k = k0 + kk;
            float2 u = r[k];
            float2 v = cmul(r[k + 2], kk ? mpos_i(U2) : U2);
            r[k] = cadd(u, v);
            r[k + 2] = csub(u, v);
        }
    }
    // stage B+2: pairs (k,k+4), twiddle U1 * e^{+i pi k/4}
#pragma unroll
    for (int k = 0; k < 4; ++k) {
        float2 tw = (k == 0) ? U1 : (k == 1) ? U1b : (k == 2) ? mpos_i(U1) : mpos_i(U1b);
        float2 u = r[k];
        float2 v = cmul(r[k + 4], tw);
        r[k] = cadd(u, v);
        r[k + 4] = csub(u, v);
    }
    if (STORE) {
#pragma unroll
        for (int k = 0; k < 8; ++k) a[pass_addr<B>(sb, k)] = r[k];
    }
}

// Z1 = W_k, Z2 = W_{16384-k} of combined x+i*f spectrum -> Yhat_k = Xhat_k*Fhat_k*scale.
__device__ __forceinline__ float2 pw(float2 z1, float2 z2, float scale) {
    float2 X = make_float2(0.5f * (z1.x + z2.x), 0.5f * (z1.y - z2.y));
    float2 D = make_float2(z1.x - z2.x, z1.y + z2.y);
    float2 F = make_float2(0.5f * D.y, -0.5f * D.x);
    float2 Y = cmul(X, F);
    return make_float2(Y.x * scale, Y.y * scale);
}

// irfft pack: G = (P + conj Q) + i*E*(P - conj Q)
__device__ __forceinline__ float2 gpack(float2 P, float2 Q, float2 E) {
    float2 S  = make_float2(P.x + Q.x, P.y - Q.y);
    float2 Dd = make_float2(P.x - Q.x, P.y + Q.y);
    float2 iE = make_float2(-E.y, E.x);
    return cadd(S, cmul(iE, Dd));
}

__global__ void __launch_bounds__(NT)
fftconv_kernel(const float* __restrict__ x, const float* __restrict__ f,
               const int* __restrict__ pos, float* __restrict__ out) {
    __shared__ float2 A[N_FFT];                 // We spectrum / G / inverse workspace
    __shared__ float2 Bb[N_FFT];                // Wo spectrum
    const int t   = threadIdx.x;
    const int cch = blockIdx.x;                 // channel b*256 + d
    const int bb  = cch >> 8;
    const size_t gbase = (size_t)cch * N_FFT;

    const float scale = 1.0f / (16384.0f * 16384.0f);  // two forward-norm 1/n factors
    const int st = swz(t);
    float2 r[8];

    // cos/sin(pi*q/8) for the odd-branch modulation (m = q*1024 + t)
    const float C8[8] = {1.0f, 0.92387953f, 0.70710678f, 0.38268343f,
                         0.0f, -0.38268343f, -0.70710678f, -0.92387953f};
    const float S8[8] = {0.0f, 0.38268343f, 0.70710678f, 0.92387953f,
                         1.0f, 0.92387953f, 0.70710678f, 0.38268343f};

    // ---- load x,f once; A = w = x + i f;  B = w * e^{-i pi m/8192} ----
    {
        float sn, cs;
        __sincosf(-PI_F * (float)t / 8192.0f, &sn, &cs);
        const float2 Bt = make_float2(cs, sn);
#pragma unroll
        for (int q = 0; q < NPT; ++q) {
            const int m = q * NT + t;
            const float2 wq = make_float2(x[gbase + m], f[gbase + m]);
            A[st + q * NT] = wq;
            const float2 tw = cmul(Bt, make_float2(C8[q], -S8[q]));  // e^{-i pi m/8192}
            Bb[st + q * NT] = cmul(wq, tw);
        }
    }
    __syncthreads();

    // ---- forward FFTs (shared barriers): A -> We (even bins), B -> Wo (odd bins) ----
    fwd_pass<10, false>(A, t); fwd_pass<10, false>(Bb, t); __syncthreads();
    fwd_pass<7,  false>(A, t); fwd_pass<7,  false>(Bb, t); __syncthreads();
    fwd_pass<4,  false>(A, t); fwd_pass<4,  false>(Bb, t); __syncthreads();
    fwd_pass<1,  true >(A, t); fwd_pass<1,  true >(Bb, t); __syncthreads();

    // ---- pointwise + irfft pack: build Ghat (bitrev) into A ----
    // cluster j handles Yprod bins {2j, 8192-2j} (from A=We) and {2j+1, 8191-2j} (from B=Wo).
    // Thread->cluster map spreads rev13(j)'s bank bits across lanes (~8-way conflicts).
    {
        float2 Gv[8];
        int    Ga[8];
        const float DC = 0.99999992646f;        // cos(pi/8192)
        const float DS = 3.83495188e-4f;        // sin(pi/8192)
#pragma unroll
        for (int q = 0; q < 2; ++q) {
            const int j = (q << 10) | ((t & 7) << 7) | (t >> 3);   // bijective [0,2048)
            const int b = rev13(j);
            float sn, cs;
            __sincosf(PI_F * (float)j / 4096.0f, &sn, &cs);
            const float2 E  = make_float2(cs, sn);                 // e^{i pi 2j/8192}
            const float2 Eo = cmul(E, make_float2(DC, DS));        // e^{i pi (2j+1)/8192}

            if (j == 0) {
                // specials: G_0 (from Ye[0], Ye[4096]) and G_4096 (= 2 conj(Ye[2048]))
                float2 a0 = A[swz(0)], a1 = A[swz(1)], a2 = A[swz(2)], a3 = A[swz(3)];
                float2 P0 = pw(a0, a0, scale);     // Ye[0]
                float2 Q0 = pw(a1, a1, scale);     // Ye[4096]
                float2 P2 = pw(a2, a3, scale);     // Ye[2048] (pair We[2048],We[6144])
                Gv[0] = gpack(P0, Q0, make_float2(1.0f, 0.0f)); Ga[0] = 0;   // rev13(0)
                Gv[1] = make_float2(2.0f * P2.x, -2.0f * P2.y); Ga[1] = 1;   // rev13(4096)
            } else {
                const int c = rev13(4096 - j);
                float2 z1 = A[swz(b)];       // We[j]
                float2 z2 = A[swz(c + 1)];   // We[8192-j]
                float2 z3 = A[swz(c)];       // We[4096-j]
                float2 z4 = A[swz(b + 1)];   // We[4096+j]
                float2 P = pw(z1, z2, scale);                    // Yprod_{2j}
                float2 Q = pw(z3, z4, scale);                    // Yprod_{8192-2j}
                Gv[q * 4 + 0] = gpack(P, Q, E);                       Ga[q * 4 + 0] = b >> 1;      // rev13(2j)
                Gv[q * 4 + 1] = gpack(Q, P, make_float2(-E.x, E.y));  Ga[q * 4 + 1] = c >> 1;      // rev13(8192-2j)
            }
            {   // odd cluster (no specials): bins 2j+1 and 8191-2j
                const int na = 8191 - b;      // rev13(8191-j)
                float2 z1 = Bb[swz(b)];       // Wo[j]
                float2 z2 = Bb[swz(na)];      // Wo[8191-j]
                float2 z3 = Bb[swz(na - 1)];  // Wo[4095-j]
                float2 z4 = Bb[swz(b + 1)];   // Wo[4096+j]
                float2 P = pw(z1, z2, scale);                    // Yprod_{2j+1}
                float2 Q = pw(z3, z4, scale);                    // Yprod_{8191-2j}
                Gv[q * 4 + 2] = gpack(P, Q, Eo);                        Ga[q * 4 + 2] = (b >> 1) | 4096;  // rev13(2j+1)
                Gv[q * 4 + 3] = gpack(Q, P, make_float2(-Eo.x, Eo.y));  Ga[q * 4 + 3] = 8191 - (b >> 1);  // rev13(8191-2j)
            }
        }
        __syncthreads();   // all We/Wo reads complete before overwriting A with G
#pragma unroll
        for (int u = 0; u < 8; ++u) A[swz(Ga[u])] = Gv[u];
    }
    __syncthreads();

    // ---- c = IDFT_8192(Ghat): c_j = y_{2j} + i y_{2j+1} ----
    inv_pass<1,  true,  true >(A, t, r); __syncthreads();
    inv_pass<4,  false, true >(A, t, r); __syncthreads();
    inv_pass<7,  false, true >(A, t, r); __syncthreads();
    inv_pass<10, false, false>(A, t, r);

    // ---- store first half (j < 4096 <=> m < 8192), masked, coalesced float2 ----
    {
        float2* out2 = (float2*)out + (size_t)cch * 4096;
        const int2* pos2 = (const int2*)(pos) + (size_t)bb * 4096;
#pragma unroll
        for (int k = 0; k < 4; ++k) {
            const int j = k * NT + t;            // r[k] = c at index k*1024 + t
            const int2 pp = pos2[j];
            const float2 v = r[k];
            out2[j] = make_float2(pp.x != -1 ? v.x : 0.0f,
                                  pp.y != -1 ? v.y : 0.0f);
        }
    }
}

extern "C" void kernel_launch(void* const* d_in, const int* in_sizes, int n_in,
                              void* d_out, int out_size, void* d_ws, size_t ws_size,
                              hipStream_t stream) {
    const float* x   = (const float*)d_in[0];
    const float* f   = (const float*)d_in[1];
    const int*   pos = (const int*)d_in[2];
    float*       out = (float*)d_out;
    (void)in_sizes; (void)n_in; (void)out_size; (void)d_ws; (void)ws_size;

    // B*D = 8*256 = 2048 channels, one block each
    fftconv_kernel<<<2048, NT, 0, stream>>>(x, f, pos, out);
}